// Round 5
// baseline (302.149 us; speedup 1.0000x reference)
//
#include <hip/hip_runtime.h>

#define N_NODES 100000
#define D_SRC 128
#define D_OUT 256
#define K_DIM 256   // D_DST + D_SRC
#define CAP 32      // bucket capacity per node (Poisson(6): P(deg>32) ~ 1e-15)
#define OVF_CAP 2048

typedef __attribute__((ext_vector_type(8))) short short8;
typedef __attribute__((ext_vector_type(4))) float float4v;
typedef __attribute__((ext_vector_type(4))) unsigned int uint4v;

__device__ inline unsigned short f2bf(float f) {
    unsigned int u = __float_as_uint(f);
    u += 0x7FFF + ((u >> 16) & 1);   // round-to-nearest-even
    return (unsigned short)(u >> 16);
}
__device__ inline float bf_lo(unsigned int u) { return __uint_as_float(u << 16); }
__device__ inline float bf_hi(unsigned int u) { return __uint_as_float(u & 0xFFFF0000u); }

// ---------------------------------------------------------------------------
// Kernel 1 (fused prep): one launch does all independent elementwise work:
//   blocks [0, 12500)      : x_src fp32 -> bf16 linear pack (xsb)
//   blocks [12500, 18750)  : x_dst fp32 -> bf16 MFMA-fragment pack (xdsw)
//   blocks [18750, 18782)  : W fp32 -> bf16 MFMA-fragment pack (wsw)
//   blocks [18782, 18880)  : zero deg + ovf_cnt (int4 stores)
// ---------------------------------------------------------------------------
#define PREP_SRC_BLOCKS 12500              // N*128/4 float4 / 256
#define PREP_DST_BLOCKS 6250               // N*16 threads / 256
#define PREP_W_BLOCKS   32                 // 256*256/8 / 256
#define PREP_Z_BLOCKS   98                 // ceil((N+4)/4 int4 / 256)
#define PREP_BLOCKS (PREP_SRC_BLOCKS + PREP_DST_BLOCKS + PREP_W_BLOCKS + PREP_Z_BLOCKS)

__global__ __launch_bounds__(256) void prep_kernel(
    const float* __restrict__ x_src,
    const float* __restrict__ x_dst,
    const float* __restrict__ W,
    unsigned short* __restrict__ xsb,
    unsigned short* __restrict__ xdsw,
    unsigned short* __restrict__ wsw,
    int* __restrict__ deg)             // zeroes N_NODES+4 ints (deg + ovf_cnt)
{
    int b = blockIdx.x;
    if (b < PREP_SRC_BLOCKS) {
        int i = b * 256 + threadIdx.x;
        float4 v = ((const float4*)x_src)[i];
        ushort4 o;
        o.x = f2bf(v.x); o.y = f2bf(v.y); o.z = f2bf(v.z); o.w = f2bf(v.w);
        ((ushort4*)xsb)[i] = o;
    } else if (b < PREP_SRC_BLOCKS + PREP_DST_BLOCKS) {
        // granule ((r>>4)*4 + kc)*64 + (r&15) + 16*sub  <- x_dst[r][kc*32+sub*8+j]
        int t = (b - PREP_SRC_BLOCKS) * 256 + threadIdx.x;
        int r = t >> 4;
        int g = t & 15;
        const float4* p = (const float4*)(x_dst + (size_t)r * 128 + g * 8);
        float4 v0 = p[0], v1 = p[1];
        union { unsigned short s[8]; short8 v; } pk;
        pk.s[0] = f2bf(v0.x); pk.s[1] = f2bf(v0.y);
        pk.s[2] = f2bf(v0.z); pk.s[3] = f2bf(v0.w);
        pk.s[4] = f2bf(v1.x); pk.s[5] = f2bf(v1.y);
        pk.s[6] = f2bf(v1.z); pk.s[7] = f2bf(v1.w);
        size_t gr = ((size_t)(r >> 4) * 4 + (g >> 2)) * 64 + (r & 15) + ((g & 3) << 4);
        ((short8*)xdsw)[gr] = pk.v;
    } else if (b < PREP_SRC_BLOCKS + PREP_DST_BLOCKS + PREP_W_BLOCKS) {
        // granule ((r>>4)*8 + kc)*64 + (r&15) + 16*sub  (r = out-row)
        int t = (b - PREP_SRC_BLOCKS - PREP_DST_BLOCKS) * 256 + threadIdx.x;
        int r = t >> 5;
        int g = t & 31;
        const float4* p = (const float4*)(W + (size_t)r * 256 + g * 8);
        float4 v0 = p[0], v1 = p[1];
        union { unsigned short s[8]; short8 v; } pk;
        pk.s[0] = f2bf(v0.x); pk.s[1] = f2bf(v0.y);
        pk.s[2] = f2bf(v0.z); pk.s[3] = f2bf(v0.w);
        pk.s[4] = f2bf(v1.x); pk.s[5] = f2bf(v1.y);
        pk.s[6] = f2bf(v1.z); pk.s[7] = f2bf(v1.w);
        size_t gr = ((size_t)(r >> 4) * 8 + (g >> 2)) * 64 + (r & 15) + ((g & 3) << 4);
        ((short8*)wsw)[gr] = pk.v;
    } else {
        int i = (b - PREP_SRC_BLOCKS - PREP_DST_BLOCKS - PREP_W_BLOCKS) * 256 + threadIdx.x;
        if (i < (N_NODES + 4) / 4)
            ((int4*)deg)[i] = make_int4(0, 0, 0, 0);
    }
}

// ---------------------------------------------------------------------------
// Kernel 2: bucket edges by dst. (unchanged)
// ---------------------------------------------------------------------------
__global__ __launch_bounds__(256) void bucket_kernel(
    const int* __restrict__ ei,     // [2, E]
    int* __restrict__ deg,          // [N] (pre-zeroed)
    int* __restrict__ ovf_cnt,      // [1] (pre-zeroed)
    int* __restrict__ ovf,          // [OVF_CAP*2]
    int* __restrict__ bucket,       // [N*CAP]
    int n_edges)
{
    int e = blockIdx.x * 256 + threadIdx.x;
    if (e >= n_edges) return;
    int s = ei[e];
    int d = ei[n_edges + e];
    int pos = atomicAdd(deg + d, 1);
    if (pos < CAP) {
        bucket[(size_t)d * CAP + pos] = s;
    } else {
        int o = atomicAdd(ovf_cnt, 1);
        if (o < OVF_CAP) { ovf[2 * o] = s; ovf[2 * o + 1] = d; }
    }
}

// ---------------------------------------------------------------------------
// Gather helper macros (4 nodes per wave; grp = lane>>4 row-slot,
// gcol = lane&15 16B chunk). Proven in round 4's standalone gather.
// ---------------------------------------------------------------------------
#define G_ISSUE(U, V, B)                                                      \
    {                                                                         \
        int r_ = (B) + grp;                                                   \
        { bool v_ = r_ < n0; V[0] = v_; int s_ = __shfl(idx0, r_);            \
          s_ = v_ ? s_ : 0;                                                   \
          U[0] = *(const uint4v*)(xsb + (size_t)s_ * D_SRC + gcol * 8); }     \
        { bool v_ = r_ < n1; V[1] = v_; int s_ = __shfl(idx1, r_);            \
          s_ = v_ ? s_ : 0;                                                   \
          U[1] = *(const uint4v*)(xsb + (size_t)s_ * D_SRC + gcol * 8); }     \
        { bool v_ = r_ < n2; V[2] = v_; int s_ = __shfl(idx2, r_);            \
          s_ = v_ ? s_ : 0;                                                   \
          U[2] = *(const uint4v*)(xsb + (size_t)s_ * D_SRC + gcol * 8); }     \
        { bool v_ = r_ < n3; V[3] = v_; int s_ = __shfl(idx3, r_);            \
          s_ = v_ ? s_ : 0;                                                   \
          U[3] = *(const uint4v*)(xsb + (size_t)s_ * D_SRC + gcol * 8); }     \
    }

#define G_ACC1(ACC, W)                                                       \
    ACC[0] += bf_lo(W[0]); ACC[1] += bf_hi(W[0]);                            \
    ACC[2] += bf_lo(W[1]); ACC[3] += bf_hi(W[1]);                            \
    ACC[4] += bf_lo(W[2]); ACC[5] += bf_hi(W[2]);                            \
    ACC[6] += bf_lo(W[3]); ACC[7] += bf_hi(W[3]);

#define G_ACCUM(U, V)                                                        \
    if (V[0]) { G_ACC1(acc0, U[0]) }                                         \
    if (V[1]) { G_ACC1(acc1, U[1]) }                                         \
    if (V[2]) { G_ACC1(acc2, U[2]) }                                         \
    if (V[3]) { G_ACC1(acc3, U[3]) }

// ---------------------------------------------------------------------------
// Kernel 3 (FUSED gather + GEMM): per 64-row tile, the block's 4 waves
// gather-mean their 16 nodes each into a 16KB LDS tile laid out in MFMA
// fragment-granule order, sync once, then run the register-double-buffered
// MFMA loop with kc<4 A from xdsw (global) and kc>=4 A from LDS.
// Eliminates the aggsw HBM round trip (51.2 MB) + one launch; gather's
// memory stalls overlap with other blocks' MFMA phases on the same CU.
// ---------------------------------------------------------------------------
__global__ __launch_bounds__(256) void fused_gather_gemm_kernel(
    const unsigned short* __restrict__ xsb,  // [N, 128] bf16 linear
    const int*   __restrict__ deg,      // [N]
    const int*   __restrict__ bucket,   // [N*CAP]
    const int*   __restrict__ ovf_cnt,  // [1]
    const int*   __restrict__ ovf,      // [OVF_CAP*2]
    const short8* __restrict__ xdsw,    // [N/16][4][64] granules
    const short8* __restrict__ wsw,     // [16][8][64] granules
    const float* __restrict__ bias,     // [256]
    float*       __restrict__ out)      // [N, 256] fp32
{
    __shared__ uint4v lds_agg[1024];    // 16KB: 64-node agg tile, granule order
    __shared__ float eps[4][16][68];    // 17.4KB epilogue staging

    const int wave = threadIdx.x >> 6;
    const int lane = threadIdx.x & 63;
    const int mb   = blockIdx.x;        // 64-row tile
    const int m0   = mb * 64;
    const int grp  = lane >> 4;         // 0..3
    const int gcol = lane & 15;         // 16B chunk within row
    const int lrow = lane & 15;
    const int kq   = lane >> 4;
    const int nc0  = wave * 64;         // output column block

    bool mok[4];
    #pragma unroll
    for (int mf = 0; mf < 4; ++mf) mok[mf] = (m0 + mf * 16) < N_NODES;

    const short8* Ax = xdsw + (size_t)mb * 1024 + lane;    // + mf*256 + kc*64
    const short8* Bw = wsw  + (size_t)wave * 2048 + lane;  // + nf*512 + kc*64

    // issue first MFMA operand loads NOW so they fly under gather latency
    const short8 zfrag = (short8){0,0,0,0,0,0,0,0};
    short8 a[2][4], b[2][4];
    #pragma unroll
    for (int mf = 0; mf < 4; ++mf)
        a[0][mf] = mok[mf] ? Ax[mf * 256] : zfrag;
    #pragma unroll
    for (int nf = 0; nf < 4; ++nf)
        b[0][nf] = Bw[nf * 512];

    // ---------------- gather phase: this wave's 16 nodes (4 quads) --------
    for (int q = 0; q < 4; ++q) {
        int nbase = m0 + wave * 16 + q * 4;

        int dl = 0;
        { int nidx = nbase + (lane & 3);
          if (nidx < N_NODES) dl = deg[nidx]; }       // invalid node -> deg 0
        int dt0 = __shfl(dl, 0), dt1 = __shfl(dl, 1);
        int dt2 = __shfl(dl, 2), dt3 = __shfl(dl, 3);
        int n0 = min(dt0, CAP), n1 = min(dt1, CAP);
        int n2 = min(dt2, CAP), n3 = min(dt3, CAP);

        // bucket rows (OOB for tail nodes reads allocated ws; values unused)
        int idx0 = bucket[(size_t)(nbase + 0) * CAP + (lane & 31)];
        int idx1 = bucket[(size_t)(nbase + 1) * CAP + (lane & 31)];
        int idx2 = bucket[(size_t)(nbase + 2) * CAP + (lane & 31)];
        int idx3 = bucket[(size_t)(nbase + 3) * CAP + (lane & 31)];

        float acc0[8] = {0,0,0,0,0,0,0,0}, acc1[8] = {0,0,0,0,0,0,0,0};
        float acc2[8] = {0,0,0,0,0,0,0,0}, acc3[8] = {0,0,0,0,0,0,0,0};

        int maxn = max(max(n0, n1), max(n2, n3));

        uint4v uA[4], uB[4];
        bool   vA[4], vB[4];
        if (maxn > 0) {
            G_ISSUE(uA, vA, 0)
            int bb = 0;
            while (true) {
                if (bb + 4 < maxn) { G_ISSUE(uB, vB, bb + 4) }
                G_ACCUM(uA, vA)
                bb += 4;
                if (bb >= maxn) break;
                if (bb + 4 < maxn) { G_ISSUE(uA, vA, bb + 4) }
                G_ACCUM(uB, vB)
                bb += 4;
                if (bb >= maxn) break;
            }
        }

        // overflow fallback (astronomically rare)
        if ((dt0 > CAP) | (dt1 > CAP) | (dt2 > CAP) | (dt3 > CAP)) {
            int oc = *ovf_cnt;
            if (oc > OVF_CAP) oc = OVF_CAP;
            for (int o = 0; o < oc; ++o) {
                int od  = ovf[2 * o + 1];
                int rel = od - nbase;
                if (rel >= 0 && rel < 4) {
                    int s0 = ovf[2 * o];
                    uint4v w = *(const uint4v*)(xsb + (size_t)s0 * D_SRC + gcol * 8);
                    if (grp == 0) {   // add once; butterfly distributes it
                        if      (rel == 0) { G_ACC1(acc0, w) }
                        else if (rel == 1) { G_ACC1(acc1, w) }
                        else if (rel == 2) { G_ACC1(acc2, w) }
                        else               { G_ACC1(acc3, w) }
                    }
                }
            }
        }

        // butterfly-reduce across the 4 row-groups (lanes ^16, ^32)
        #pragma unroll
        for (int k = 0; k < 8; ++k) {
            acc0[k] += __shfl_xor(acc0[k], 16); acc0[k] += __shfl_xor(acc0[k], 32);
            acc1[k] += __shfl_xor(acc1[k], 16); acc1[k] += __shfl_xor(acc1[k], 32);
            acc2[k] += __shfl_xor(acc2[k], 16); acc2[k] += __shfl_xor(acc2[k], 32);
            acc3[k] += __shfl_xor(acc3[k], 16); acc3[k] += __shfl_xor(acc3[k], 32);
        }

        int dsel = dt0;
        dsel = (grp == 1) ? dt1 : dsel;
        dsel = (grp == 2) ? dt2 : dsel;
        dsel = (grp == 3) ? dt3 : dsel;
        float inv = 1.0f / (float)((dsel > 1) ? dsel : 1);

        float sum[8];
        #pragma unroll
        for (int k = 0; k < 8; ++k) {
            float v = acc0[k];
            v = (grp == 1) ? acc1[k] : v;
            v = (grp == 2) ? acc2[k] : v;
            v = (grp == 3) ? acc3[k] : v;
            sum[k] = v * inv;
        }

        uint4v o;
        o[0] = (unsigned)f2bf(sum[0]) | ((unsigned)f2bf(sum[1]) << 16);
        o[1] = (unsigned)f2bf(sum[2]) | ((unsigned)f2bf(sum[3]) << 16);
        o[2] = (unsigned)f2bf(sum[4]) | ((unsigned)f2bf(sum[5]) << 16);
        o[3] = (unsigned)f2bf(sum[6]) | ((unsigned)f2bf(sum[7]) << 16);

        // LDS granule: ((t>>4)*4 + kc')*64 + (t&15) + 16*sub,
        // t = wave*16+q*4+grp -> t>>4 = wave, t&15 = q*4+grp; kc'=gcol>>2,
        // sub = gcol&3. Matches MFMA read granule (mf*4+kk)*64 + lane.
        int gr = (wave * 4 + (gcol >> 2)) * 64 + (q * 4 + grp) + ((gcol & 3) << 4);
        lds_agg[gr] = o;
    }

    __syncthreads();   // all 64 rows' agg visible to all waves

    // ---------------- MFMA phase ----------------
    float4v acc[4][4];
    #pragma unroll
    for (int i = 0; i < 4; ++i)
        #pragma unroll
        for (int j = 0; j < 4; ++j)
            acc[i][j] = (float4v){0.f, 0.f, 0.f, 0.f};

    #pragma unroll
    for (int kc = 0; kc < 8; ++kc) {
        const int cur = kc & 1, nxt = cur ^ 1;
        if (kc < 7) {
            const int k1 = kc + 1;
            if (k1 < 4) {
                #pragma unroll
                for (int mf = 0; mf < 4; ++mf)
                    a[nxt][mf] = mok[mf] ? Ax[mf * 256 + k1 * 64] : zfrag;
            } else {
                const int kk = k1 - 4;
                #pragma unroll
                for (int mf = 0; mf < 4; ++mf)
                    a[nxt][mf] = *(const short8*)&lds_agg[(mf * 4 + kk) * 64 + lane];
            }
            #pragma unroll
            for (int nf = 0; nf < 4; ++nf)
                b[nxt][nf] = Bw[nf * 512 + k1 * 64];
        }
        #pragma unroll
        for (int mf = 0; mf < 4; ++mf)
            #pragma unroll
            for (int nf = 0; nf < 4; ++nf)
                acc[mf][nf] = __builtin_amdgcn_mfma_f32_16x16x32_bf16(
                    a[cur][mf], b[cur][nf], acc[mf][nf], 0, 0, 0);
    }

    // ---- epilogue: bias+relu, wave-private LDS bounce, 256B nt stores ----
    float bv[4];
    #pragma unroll
    for (int nf = 0; nf < 4; ++nf)
        bv[nf] = bias[nc0 + nf * 16 + lrow];

    int srow   = lane >> 4;     // 0..3
    int schunk = lane & 15;     // 16B units across 64 cols

    #pragma unroll
    for (int mf = 0; mf < 4; ++mf) {
        if (!mok[mf]) continue;   // block-uniform
        #pragma unroll
        for (int nf = 0; nf < 4; ++nf)
            #pragma unroll
            for (int r = 0; r < 4; ++r)
                eps[wave][kq * 4 + r][nf * 16 + lrow] =
                    fmaxf(acc[mf][nf][r] + bv[nf], 0.f);
        asm volatile("s_waitcnt lgkmcnt(0)" ::: "memory");
        #pragma unroll
        for (int c = 0; c < 4; ++c) {
            int row  = c * 4 + srow;
            float4v v = *(const float4v*)&eps[wave][row][schunk * 4];
            int grow = m0 + mf * 16 + row;
            __builtin_nontemporal_store(v,
                (float4v*)(out + (size_t)grow * D_OUT + nc0 + schunk * 4));
        }
        asm volatile("s_waitcnt lgkmcnt(0)" ::: "memory");
    }
}

extern "C" void kernel_launch(void* const* d_in, const int* in_sizes, int n_in,
                              void* d_out, int out_size, void* d_ws, size_t ws_size,
                              hipStream_t stream) {
    const float* x_src = (const float*)d_in[0];
    const float* x_dst = (const float*)d_in[1];
    const int*   ei    = (const int*)d_in[2];
    const float* W     = (const float*)d_in[3];
    const float* bias  = (const float*)d_in[4];
    float* out = (float*)d_out;

    int n_edges = in_sizes[2] / 2;

    // workspace layout (ws, ~64.5 MB total; observed ws poison = 400 MB):
    //   deg    : N_NODES int           (zeroed by prep)
    //   ovf_cnt: 4 int                 (zeroed by prep)
    //   ovf    : OVF_CAP*2 int
    //   wsw    : 256*256 ushort  (bf16 W, fragment order)
    //   xdsw   : N/16*4*64*8 ushort (bf16 x_dst, fragment order)
    //   bucket : N_NODES*CAP int
    //   xsb    : N_NODES*128 ushort (bf16 x_src, linear)
    // (bucket/xsb no longer alias d_out: the fused kernel reads them while
    //  writing out.)
    int* deg     = (int*)d_ws;
    int* ovf_cnt = deg + N_NODES;
    int* ovf     = ovf_cnt + 4;
    unsigned short* wsw  = (unsigned short*)(ovf + OVF_CAP * 2);
    unsigned short* xdsw = wsw + (size_t)D_OUT * K_DIM;
    int* bucket = (int*)(xdsw + (size_t)(N_NODES / 16) * 4 * 64 * 8);
    unsigned short* xsb = (unsigned short*)(bucket + (size_t)N_NODES * CAP);

    prep_kernel<<<PREP_BLOCKS, 256, 0, stream>>>(
        x_src, x_dst, W, xsb, xdsw, wsw, deg);

    bucket_kernel<<<(n_edges + 255) / 256, 256, 0, stream>>>(
        ei, deg, ovf_cnt, ovf, bucket, n_edges);

    fused_gather_gemm_kernel<<<(N_NODES + 63) / 64, 256, 0, stream>>>(
        xsb, deg, bucket, ovf_cnt, ovf,
        (const short8*)xdsw, (const short8*)wsw, bias, out);
}

// Round 6
// 286.200 us; speedup vs baseline: 1.0557x; 1.0557x over previous
//
#include <hip/hip_runtime.h>

#define N_NODES 100000
#define D_SRC 128
#define D_OUT 256
#define K_DIM 256   // D_DST + D_SRC
#define CAP 32      // bucket capacity per node (Poisson(6): P(deg>32) ~ 1e-15)
#define OVF_CAP 2048

typedef __attribute__((ext_vector_type(8))) short short8;
typedef __attribute__((ext_vector_type(4))) float float4v;
typedef __attribute__((ext_vector_type(4))) unsigned int uint4v;

__device__ inline unsigned short f2bf(float f) {
    unsigned int u = __float_as_uint(f);
    u += 0x7FFF + ((u >> 16) & 1);   // round-to-nearest-even
    return (unsigned short)(u >> 16);
}
__device__ inline float bf_lo(unsigned int u) { return __uint_as_float(u << 16); }
__device__ inline float bf_hi(unsigned int u) { return __uint_as_float(u & 0xFFFF0000u); }

// ---------------------------------------------------------------------------
// Kernel 1 (fused prep): one launch does all independent elementwise work:
//   blocks [0, 12500)      : x_src fp32 -> bf16 linear pack (xsb)
//   blocks [12500, 18750)  : x_dst fp32 -> bf16 MFMA-fragment pack (xdsw)
//   blocks [18750, 18782)  : W fp32 -> bf16 MFMA-fragment pack (wsw)
//   blocks [18782, 18880)  : zero deg + ovf_cnt (int4 stores)
// ---------------------------------------------------------------------------
#define PREP_SRC_BLOCKS 12500              // N*128/4 float4 / 256
#define PREP_DST_BLOCKS 6250               // N*16 threads / 256
#define PREP_W_BLOCKS   32                 // 256*256/8 / 256
#define PREP_Z_BLOCKS   98                 // ceil((N+4)/4 int4 / 256)
#define PREP_BLOCKS (PREP_SRC_BLOCKS + PREP_DST_BLOCKS + PREP_W_BLOCKS + PREP_Z_BLOCKS)

__global__ __launch_bounds__(256) void prep_kernel(
    const float* __restrict__ x_src,
    const float* __restrict__ x_dst,
    const float* __restrict__ W,
    unsigned short* __restrict__ xsb,
    unsigned short* __restrict__ xdsw,
    unsigned short* __restrict__ wsw,
    int* __restrict__ deg)             // zeroes N_NODES+4 ints (deg + ovf_cnt)
{
    int b = blockIdx.x;
    if (b < PREP_SRC_BLOCKS) {
        int i = b * 256 + threadIdx.x;
        float4 v = ((const float4*)x_src)[i];
        ushort4 o;
        o.x = f2bf(v.x); o.y = f2bf(v.y); o.z = f2bf(v.z); o.w = f2bf(v.w);
        ((ushort4*)xsb)[i] = o;
    } else if (b < PREP_SRC_BLOCKS + PREP_DST_BLOCKS) {
        // granule ((r>>4)*4 + kc)*64 + (r&15) + 16*sub  <- x_dst[r][kc*32+sub*8+j]
        int t = (b - PREP_SRC_BLOCKS) * 256 + threadIdx.x;
        int r = t >> 4;
        int g = t & 15;
        const float4* p = (const float4*)(x_dst + (size_t)r * 128 + g * 8);
        float4 v0 = p[0], v1 = p[1];
        union { unsigned short s[8]; short8 v; } pk;
        pk.s[0] = f2bf(v0.x); pk.s[1] = f2bf(v0.y);
        pk.s[2] = f2bf(v0.z); pk.s[3] = f2bf(v0.w);
        pk.s[4] = f2bf(v1.x); pk.s[5] = f2bf(v1.y);
        pk.s[6] = f2bf(v1.z); pk.s[7] = f2bf(v1.w);
        size_t gr = ((size_t)(r >> 4) * 4 + (g >> 2)) * 64 + (r & 15) + ((g & 3) << 4);
        ((short8*)xdsw)[gr] = pk.v;
    } else if (b < PREP_SRC_BLOCKS + PREP_DST_BLOCKS + PREP_W_BLOCKS) {
        // granule ((r>>4)*8 + kc)*64 + (r&15) + 16*sub  (r = out-row)
        int t = (b - PREP_SRC_BLOCKS - PREP_DST_BLOCKS) * 256 + threadIdx.x;
        int r = t >> 5;
        int g = t & 31;
        const float4* p = (const float4*)(W + (size_t)r * 256 + g * 8);
        float4 v0 = p[0], v1 = p[1];
        union { unsigned short s[8]; short8 v; } pk;
        pk.s[0] = f2bf(v0.x); pk.s[1] = f2bf(v0.y);
        pk.s[2] = f2bf(v0.z); pk.s[3] = f2bf(v0.w);
        pk.s[4] = f2bf(v1.x); pk.s[5] = f2bf(v1.y);
        pk.s[6] = f2bf(v1.z); pk.s[7] = f2bf(v1.w);
        size_t gr = ((size_t)(r >> 4) * 8 + (g >> 2)) * 64 + (r & 15) + ((g & 3) << 4);
        ((short8*)wsw)[gr] = pk.v;
    } else {
        int i = (b - PREP_SRC_BLOCKS - PREP_DST_BLOCKS - PREP_W_BLOCKS) * 256 + threadIdx.x;
        if (i < (N_NODES + 4) / 4)
            ((int4*)deg)[i] = make_int4(0, 0, 0, 0);
    }
}

// ---------------------------------------------------------------------------
// Kernel 2: bucket edges by dst — 2 edges per thread (int2 loads).
// Halves wave count; 8B coalesced loads; same atomic pattern.
// ---------------------------------------------------------------------------
__global__ __launch_bounds__(256) void bucket_kernel(
    const int* __restrict__ ei,     // [2, E]
    int* __restrict__ deg,          // [N] (pre-zeroed)
    int* __restrict__ ovf_cnt,      // [1] (pre-zeroed)
    int* __restrict__ ovf,          // [OVF_CAP*2]
    int* __restrict__ bucket,       // [N*CAP]
    int n_edges)
{
    int t = blockIdx.x * 256 + threadIdx.x;
    int e0 = 2 * t;
    if (e0 + 1 < n_edges) {
        int2 s2 = ((const int2*)ei)[t];
        int2 d2 = ((const int2*)(ei + n_edges))[t];
        int pos0 = atomicAdd(deg + d2.x, 1);
        if (pos0 < CAP) {
            bucket[(size_t)d2.x * CAP + pos0] = s2.x;
        } else {
            int o = atomicAdd(ovf_cnt, 1);
            if (o < OVF_CAP) { ovf[2 * o] = s2.x; ovf[2 * o + 1] = d2.x; }
        }
        int pos1 = atomicAdd(deg + d2.y, 1);
        if (pos1 < CAP) {
            bucket[(size_t)d2.y * CAP + pos1] = s2.y;
        } else {
            int o = atomicAdd(ovf_cnt, 1);
            if (o < OVF_CAP) { ovf[2 * o] = s2.y; ovf[2 * o + 1] = d2.y; }
        }
    } else if (e0 < n_edges) {    // odd-E tail (not hit for E=600000)
        int s = ei[e0];
        int d = ei[n_edges + e0];
        int pos = atomicAdd(deg + d, 1);
        if (pos < CAP) {
            bucket[(size_t)d * CAP + pos] = s;
        } else {
            int o = atomicAdd(ovf_cnt, 1);
            if (o < OVF_CAP) { ovf[2 * o] = s; ovf[2 * o + 1] = d; }
        }
    }
}

// ---------------------------------------------------------------------------
// Gather helper macros (quad of nodes; grp = lane>>4 row-slot,
// gcol = lane&15 16B chunk). Proven in round 4; parameterized for 2 quads.
// ---------------------------------------------------------------------------
#define G_ISSUE8(U, V, B, I0, I1, I2, I3, N0, N1, N2, N3)                     \
    {                                                                         \
        int r_ = (B) + grp;                                                   \
        { bool v_ = r_ < N0; V[0] = v_; int s_ = __shfl(I0, r_);              \
          s_ = v_ ? s_ : 0;                                                   \
          U[0] = *(const uint4v*)(xsb + (size_t)s_ * D_SRC + gcol * 8); }     \
        { bool v_ = r_ < N1; V[1] = v_; int s_ = __shfl(I1, r_);              \
          s_ = v_ ? s_ : 0;                                                   \
          U[1] = *(const uint4v*)(xsb + (size_t)s_ * D_SRC + gcol * 8); }     \
        { bool v_ = r_ < N2; V[2] = v_; int s_ = __shfl(I2, r_);              \
          s_ = v_ ? s_ : 0;                                                   \
          U[2] = *(const uint4v*)(xsb + (size_t)s_ * D_SRC + gcol * 8); }     \
        { bool v_ = r_ < N3; V[3] = v_; int s_ = __shfl(I3, r_);              \
          s_ = v_ ? s_ : 0;                                                   \
          U[3] = *(const uint4v*)(xsb + (size_t)s_ * D_SRC + gcol * 8); }     \
    }

#define G_ACC1(ACC, W)                                                       \
    ACC[0] += bf_lo(W[0]); ACC[1] += bf_hi(W[0]);                            \
    ACC[2] += bf_lo(W[1]); ACC[3] += bf_hi(W[1]);                            \
    ACC[4] += bf_lo(W[2]); ACC[5] += bf_hi(W[2]);                            \
    ACC[6] += bf_lo(W[3]); ACC[7] += bf_hi(W[3]);

#define G_ACCUM8(U, V, A0, A1, A2, A3)                                       \
    if (V[0]) { G_ACC1(A0, U[0]) }                                           \
    if (V[1]) { G_ACC1(A1, U[1]) }                                           \
    if (V[2]) { G_ACC1(A2, U[2]) }                                           \
    if (V[3]) { G_ACC1(A3, U[3]) }

// ---------------------------------------------------------------------------
// Kernel 3: gather-sum + mean, 8 NODES PER WAVE (2 interleaved quads).
// Both quads' batches are issued before either accumulates -> 2x in-flight
// loads before the first dependent use, half the per-node idx/loop overhead.
// Epilogue: butterfly per quad, static cndmask-select, two coalesced 1KB
// wave stores in fragment-granule order.
// ---------------------------------------------------------------------------
__global__ __launch_bounds__(256) void gather_kernel(
    const unsigned short* __restrict__ xsb,  // [N, 128] bf16 linear
    const int*   __restrict__ deg,      // [N]
    const int*   __restrict__ bucket,   // [N*CAP]
    const int*   __restrict__ ovf_cnt,  // [1]
    const int*   __restrict__ ovf,      // [OVF_CAP*2]
    unsigned int* __restrict__ aggsw)   // fragment-order bf16 mean (dwords)
{
    int wid  = threadIdx.x >> 6;
    int lane = threadIdx.x & 63;
    int wbase = (blockIdx.x * 4 + wid) * 8;   // 32 nodes/block; 3125 blocks exact
    int grp  = lane >> 4;                     // 0..3
    int gcol = lane & 15;                     // 16B chunk within row

    // degrees for the 8 nodes
    int dl = deg[wbase + (lane & 7)];
    int dtA0 = __shfl(dl, 0), dtA1 = __shfl(dl, 1);
    int dtA2 = __shfl(dl, 2), dtA3 = __shfl(dl, 3);
    int dtB0 = __shfl(dl, 4), dtB1 = __shfl(dl, 5);
    int dtB2 = __shfl(dl, 6), dtB3 = __shfl(dl, 7);
    int nA0 = min(dtA0, CAP), nA1 = min(dtA1, CAP);
    int nA2 = min(dtA2, CAP), nA3 = min(dtA3, CAP);
    int nB0 = min(dtB0, CAP), nB1 = min(dtB1, CAP);
    int nB2 = min(dtB2, CAP), nB3 = min(dtB3, CAP);

    // bucket rows (8 x 128B, sequential 1KB per wave)
    int iA0 = bucket[(size_t)(wbase + 0) * CAP + (lane & 31)];
    int iA1 = bucket[(size_t)(wbase + 1) * CAP + (lane & 31)];
    int iA2 = bucket[(size_t)(wbase + 2) * CAP + (lane & 31)];
    int iA3 = bucket[(size_t)(wbase + 3) * CAP + (lane & 31)];
    int iB0 = bucket[(size_t)(wbase + 4) * CAP + (lane & 31)];
    int iB1 = bucket[(size_t)(wbase + 5) * CAP + (lane & 31)];
    int iB2 = bucket[(size_t)(wbase + 6) * CAP + (lane & 31)];
    int iB3 = bucket[(size_t)(wbase + 7) * CAP + (lane & 31)];

    float accA0[8] = {0,0,0,0,0,0,0,0}, accA1[8] = {0,0,0,0,0,0,0,0};
    float accA2[8] = {0,0,0,0,0,0,0,0}, accA3[8] = {0,0,0,0,0,0,0,0};
    float accB0[8] = {0,0,0,0,0,0,0,0}, accB1[8] = {0,0,0,0,0,0,0,0};
    float accB2[8] = {0,0,0,0,0,0,0,0}, accB3[8] = {0,0,0,0,0,0,0,0};

    int maxn = max(max(max(nA0, nA1), max(nA2, nA3)),
                   max(max(nB0, nB1), max(nB2, nB3)));

    uint4v uAa[4], uAb[4], uBa[4], uBb[4];
    bool   vAa[4], vAb[4], vBa[4], vBb[4];
    if (maxn > 0) {
        G_ISSUE8(uAa, vAa, 0, iA0, iA1, iA2, iA3, nA0, nA1, nA2, nA3)
        G_ISSUE8(uBa, vBa, 0, iB0, iB1, iB2, iB3, nB0, nB1, nB2, nB3)
        int bb = 0;
        while (true) {
            if (bb + 4 < maxn) {
                G_ISSUE8(uAb, vAb, bb + 4, iA0, iA1, iA2, iA3, nA0, nA1, nA2, nA3)
                G_ISSUE8(uBb, vBb, bb + 4, iB0, iB1, iB2, iB3, nB0, nB1, nB2, nB3)
            }
            G_ACCUM8(uAa, vAa, accA0, accA1, accA2, accA3)
            G_ACCUM8(uBa, vBa, accB0, accB1, accB2, accB3)
            bb += 4;
            if (bb >= maxn) break;
            if (bb + 4 < maxn) {
                G_ISSUE8(uAa, vAa, bb + 4, iA0, iA1, iA2, iA3, nA0, nA1, nA2, nA3)
                G_ISSUE8(uBa, vBa, bb + 4, iB0, iB1, iB2, iB3, nB0, nB1, nB2, nB3)
            }
            G_ACCUM8(uAb, vAb, accA0, accA1, accA2, accA3)
            G_ACCUM8(uBb, vBb, accB0, accB1, accB2, accB3)
            bb += 4;
            if (bb >= maxn) break;
        }
    }

    // overflow fallback (astronomically rare)
    if ((dtA0 > CAP) | (dtA1 > CAP) | (dtA2 > CAP) | (dtA3 > CAP) |
        (dtB0 > CAP) | (dtB1 > CAP) | (dtB2 > CAP) | (dtB3 > CAP)) {
        int oc = *ovf_cnt;
        if (oc > OVF_CAP) oc = OVF_CAP;
        for (int o = 0; o < oc; ++o) {
            int od  = ovf[2 * o + 1];
            int rel = od - wbase;
            if (rel >= 0 && rel < 8) {
                int s0 = ovf[2 * o];
                uint4v w = *(const uint4v*)(xsb + (size_t)s0 * D_SRC + gcol * 8);
                if (grp == 0) {   // add once; butterfly distributes it
                    if      (rel == 0) { G_ACC1(accA0, w) }
                    else if (rel == 1) { G_ACC1(accA1, w) }
                    else if (rel == 2) { G_ACC1(accA2, w) }
                    else if (rel == 3) { G_ACC1(accA3, w) }
                    else if (rel == 4) { G_ACC1(accB0, w) }
                    else if (rel == 5) { G_ACC1(accB1, w) }
                    else if (rel == 6) { G_ACC1(accB2, w) }
                    else               { G_ACC1(accB3, w) }
                }
            }
        }
    }

    // butterfly-reduce across the 4 row-groups (lanes ^16, ^32)
    #pragma unroll
    for (int k = 0; k < 8; ++k) {
        accA0[k] += __shfl_xor(accA0[k], 16); accA0[k] += __shfl_xor(accA0[k], 32);
        accA1[k] += __shfl_xor(accA1[k], 16); accA1[k] += __shfl_xor(accA1[k], 32);
        accA2[k] += __shfl_xor(accA2[k], 16); accA2[k] += __shfl_xor(accA2[k], 32);
        accA3[k] += __shfl_xor(accA3[k], 16); accA3[k] += __shfl_xor(accA3[k], 32);
        accB0[k] += __shfl_xor(accB0[k], 16); accB0[k] += __shfl_xor(accB0[k], 32);
        accB1[k] += __shfl_xor(accB1[k], 16); accB1[k] += __shfl_xor(accB1[k], 32);
        accB2[k] += __shfl_xor(accB2[k], 16); accB2[k] += __shfl_xor(accB2[k], 32);
        accB3[k] += __shfl_xor(accB3[k], 16); accB3[k] += __shfl_xor(accB3[k], 32);
    }

    // quad A: lane (grp, gcol) stores granule gcol of node wbase+grp
    {
        int dsel = dtA0;
        dsel = (grp == 1) ? dtA1 : dsel;
        dsel = (grp == 2) ? dtA2 : dsel;
        dsel = (grp == 3) ? dtA3 : dsel;
        float inv = 1.0f / (float)((dsel > 1) ? dsel : 1);
        float sum[8];
        #pragma unroll
        for (int k = 0; k < 8; ++k) {
            float v = accA0[k];
            v = (grp == 1) ? accA1[k] : v;
            v = (grp == 2) ? accA2[k] : v;
            v = (grp == 3) ? accA3[k] : v;
            sum[k] = v * inv;
        }
        uint4v o;
        o[0] = (unsigned)f2bf(sum[0]) | ((unsigned)f2bf(sum[1]) << 16);
        o[1] = (unsigned)f2bf(sum[2]) | ((unsigned)f2bf(sum[3]) << 16);
        o[2] = (unsigned)f2bf(sum[4]) | ((unsigned)f2bf(sum[5]) << 16);
        o[3] = (unsigned)f2bf(sum[6]) | ((unsigned)f2bf(sum[7]) << 16);
        int node = wbase + grp;
        size_t gr = ((size_t)(node >> 4) * 4 + (gcol >> 2)) * 64
                  + (node & 15) + ((gcol & 3) << 4);
        ((uint4v*)aggsw)[gr] = o;
    }
    // quad B: node wbase+4+grp
    {
        int dsel = dtB0;
        dsel = (grp == 1) ? dtB1 : dsel;
        dsel = (grp == 2) ? dtB2 : dsel;
        dsel = (grp == 3) ? dtB3 : dsel;
        float inv = 1.0f / (float)((dsel > 1) ? dsel : 1);
        float sum[8];
        #pragma unroll
        for (int k = 0; k < 8; ++k) {
            float v = accB0[k];
            v = (grp == 1) ? accB1[k] : v;
            v = (grp == 2) ? accB2[k] : v;
            v = (grp == 3) ? accB3[k] : v;
            sum[k] = v * inv;
        }
        uint4v o;
        o[0] = (unsigned)f2bf(sum[0]) | ((unsigned)f2bf(sum[1]) << 16);
        o[1] = (unsigned)f2bf(sum[2]) | ((unsigned)f2bf(sum[3]) << 16);
        o[2] = (unsigned)f2bf(sum[4]) | ((unsigned)f2bf(sum[5]) << 16);
        o[3] = (unsigned)f2bf(sum[6]) | ((unsigned)f2bf(sum[7]) << 16);
        int node = wbase + 4 + grp;
        size_t gr = ((size_t)(node >> 4) * 4 + (gcol >> 2)) * 64
                  + (node & 15) + ((gcol & 3) << 4);
        ((uint4v*)aggsw)[gr] = o;
    }
}

// ---------------------------------------------------------------------------
// Kernel 4: MFMA GEMM (round-4 proven version, unchanged).
// ---------------------------------------------------------------------------
__global__ __launch_bounds__(256) void mfma_gemm_kernel(
    const short8* __restrict__ xdsw,   // [N/16][4][64] granules
    const short8* __restrict__ aggsw,  // [N/16][4][64] granules
    const short8* __restrict__ wsw,    // [16][8][64] granules
    const float* __restrict__ bias,    // [256]
    float*       __restrict__ out)     // [N, 256] fp32
{
    __shared__ float eps[4][16][68];   // [wave][row][col64 + pad4]

    int wave = threadIdx.x >> 6;  // column block n0 = wave*64
    int lane = threadIdx.x & 63;
    int lrow = lane & 15;
    int kq   = lane >> 4;
    int mb   = blockIdx.x;        // 64-row tile
    int m0   = mb * 64;
    int n0   = wave * 64;

    bool mok[4];
    #pragma unroll
    for (int mf = 0; mf < 4; ++mf) mok[mf] = (m0 + mf * 16) < N_NODES;

    const short8* Ax = xdsw  + (size_t)mb * 1024 + lane;   // + mf*256 + kc*64
    const short8* Ag = aggsw + (size_t)mb * 1024 + lane;   // + mf*256 + kc'*64
    const short8* Bw = wsw   + (size_t)wave * 2048 + lane; // + nf*512 + kc*64

    float4v acc[4][4];
    #pragma unroll
    for (int i = 0; i < 4; ++i)
        #pragma unroll
        for (int j = 0; j < 4; ++j)
            acc[i][j] = (float4v){0.f, 0.f, 0.f, 0.f};

    const short8 zfrag = (short8){0,0,0,0,0,0,0,0};
    short8 a[2][4], b[2][4];

    #pragma unroll
    for (int mf = 0; mf < 4; ++mf)
        a[0][mf] = mok[mf] ? Ax[mf * 256] : zfrag;
    #pragma unroll
    for (int nf = 0; nf < 4; ++nf)
        b[0][nf] = Bw[nf * 512];

    #pragma unroll
    for (int kc = 0; kc < 8; ++kc) {
        const int cur = kc & 1, nxt = cur ^ 1;
        if (kc < 7) {
            const int k1 = kc + 1;
            const short8* A = (k1 < 4) ? Ax : Ag;
            const int kk = (k1 < 4) ? k1 : (k1 - 4);
            #pragma unroll
            for (int mf = 0; mf < 4; ++mf)
                a[nxt][mf] = mok[mf] ? A[mf * 256 + kk * 64] : zfrag;
            #pragma unroll
            for (int nf = 0; nf < 4; ++nf)
                b[nxt][nf] = Bw[nf * 512 + k1 * 64];
        }
        #pragma unroll
        for (int mf = 0; mf < 4; ++mf)
            #pragma unroll
            for (int nf = 0; nf < 4; ++nf)
                acc[mf][nf] = __builtin_amdgcn_mfma_f32_16x16x32_bf16(
                    a[cur][mf], b[cur][nf], acc[mf][nf], 0, 0, 0);
    }

    // ---- epilogue: bias+relu, wave-private LDS bounce, 256B nt stores ----
    float bv[4];
    #pragma unroll
    for (int nf = 0; nf < 4; ++nf)
        bv[nf] = bias[n0 + nf * 16 + lrow];

    int srow   = lane >> 4;     // 0..3
    int schunk = lane & 15;     // 16B units across 64 cols

    #pragma unroll
    for (int mf = 0; mf < 4; ++mf) {
        if (!mok[mf]) continue;   // block-uniform
        #pragma unroll
        for (int nf = 0; nf < 4; ++nf)
            #pragma unroll
            for (int r = 0; r < 4; ++r)
                eps[wave][kq * 4 + r][nf * 16 + lrow] =
                    fmaxf(acc[mf][nf][r] + bv[nf], 0.f);
        asm volatile("s_waitcnt lgkmcnt(0)" ::: "memory");
        #pragma unroll
        for (int c = 0; c < 4; ++c) {
            int row  = c * 4 + srow;
            float4v v = *(const float4v*)&eps[wave][row][schunk * 4];
            int grow = m0 + mf * 16 + row;
            __builtin_nontemporal_store(v,
                (float4v*)(out + (size_t)grow * D_OUT + n0 + schunk * 4));
        }
        asm volatile("s_waitcnt lgkmcnt(0)" ::: "memory");
    }
}

extern "C" void kernel_launch(void* const* d_in, const int* in_sizes, int n_in,
                              void* d_out, int out_size, void* d_ws, size_t ws_size,
                              hipStream_t stream) {
    const float* x_src = (const float*)d_in[0];
    const float* x_dst = (const float*)d_in[1];
    const int*   ei    = (const int*)d_in[2];
    const float* W     = (const float*)d_in[3];
    const float* bias  = (const float*)d_in[4];
    float* out = (float*)d_out;

    int n_edges = in_sizes[2] / 2;

    // workspace layout (ws):
    //   deg    : N_NODES int           (zeroed by prep)
    //   ovf_cnt: 4 int                 (zeroed by prep)
    //   ovf    : OVF_CAP*2 int
    //   wsw    : 256*256 ushort  (bf16 W, fragment order)
    //   aggsw  : N/16*4*64*8 ushort (bf16 agg, fragment order)
    //   xdsw   : N/16*4*64*8 ushort (bf16 x_dst, fragment order)
    int* deg     = (int*)d_ws;
    int* ovf_cnt = deg + N_NODES;
    int* ovf     = ovf_cnt + 4;
    unsigned short* wsw   = (unsigned short*)(ovf + OVF_CAP * 2);
    unsigned short* aggsw = wsw + (size_t)D_OUT * K_DIM;
    unsigned short* xdsw  = aggsw + (size_t)(N_NODES / 16) * 4 * 64 * 8;

    // d_out doubles as stream-ordered scratch for buffers dead before GEMM:
    //   bucket : N_NODES*CAP int   at offset 0        (12.8 MB)
    //   xsb    : N_NODES*128 ushort at 12.8 MB        (25.6 MB)
    int* bucket = (int*)d_out;
    unsigned short* xsb = (unsigned short*)(bucket + (size_t)N_NODES * CAP);

    prep_kernel<<<PREP_BLOCKS, 256, 0, stream>>>(
        x_src, x_dst, W, xsb, xdsw, wsw, deg);

    int n_pairs = (n_edges + 1) / 2;
    bucket_kernel<<<(n_pairs + 255) / 256, 256, 0, stream>>>(
        ei, deg, ovf_cnt, ovf, bucket, n_edges);

    gather_kernel<<<(N_NODES + 31) / 32, 256, 0, stream>>>(
        xsb, deg, bucket, ovf_cnt, ovf, (unsigned int*)aggsw);

    mfma_gemm_kernel<<<(N_NODES + 63) / 64, 256, 0, stream>>>(
        (const short8*)xdsw, (const short8*)aggsw, (const short8*)wsw, bias, out);
}